// Round 1
// baseline (3610.505 us; speedup 1.0000x reference)
//
#include <hip/hip_runtime.h>

// VQ nearest-codebook search, fp32 baseline.
// score(n,k) = 0.5*|e_k|^2 - z_n . e_k   (monotone in squared distance)
// Kernel 1: half-norms of embedding rows -> d_ws
// Kernel 2: per block 64 tokens (8 waves x 8 tokens); loop 128 tiles of 64 codes;
//           e-tile staged in LDS (stride-68 pad, conflict-free b128),
//           z read via wave-uniform (scalar) loads; per-lane running argmin;
//           64-lane shuffle reduce + coalesced gather of winning rows.

#define C 256            // token/code dim
#define THREADS 512      // 8 waves
#define EPAD 68          // 64 + 4 floats pad: lane stride 272B -> start bank 4*lane%32

__global__ __launch_bounds__(64) void vq_norms(const float* __restrict__ emb,
                                               float* __restrict__ hn) {
    const int k = blockIdx.x;
    const int lane = threadIdx.x;
    const float4 v = *reinterpret_cast<const float4*>(emb + (size_t)k * C + lane * 4);
    float s = v.x * v.x + v.y * v.y + v.z * v.z + v.w * v.w;
    #pragma unroll
    for (int off = 32; off; off >>= 1) s += __shfl_down(s, off);
    if (lane == 0) hn[k] = 0.5f * s;
}

__global__ __launch_bounds__(THREADS) void vq_main(const float* __restrict__ z,
                                                   const float* __restrict__ emb,
                                                   const float* __restrict__ hn,
                                                   float* __restrict__ out,
                                                   int K) {
    __shared__ float elds[64 * EPAD];

    const int tid = threadIdx.x;
    const int lane = tid & 63;
    // wave id forced uniform so z addresses scalarize to s_load
    const int wid = __builtin_amdgcn_readfirstlane(tid >> 6);
    const int token_base = blockIdx.x * 64 + wid * 8;
    const float* zw = z + (size_t)token_base * C;

    float best_s[8];
    int best_i[8];
    #pragma unroll
    for (int t = 0; t < 8; ++t) { best_s[t] = 3.4e38f; best_i[t] = 0; }

    const int ntiles = K >> 6;  // 128
    #pragma unroll 1
    for (int tile = 0; tile < ntiles; ++tile) {
        float acc[8];
        #pragma unroll
        for (int t = 0; t < 8; ++t) acc[t] = 0.f;

        #pragma unroll 1
        for (int ck = 0; ck < 4; ++ck) {  // 4 chunks of 64 c-values
            __syncthreads();
            // stage e chunk [64 codes][64 c] -> LDS, 2 float4 per thread
            #pragma unroll
            for (int i = 0; i < 2; ++i) {
                const int slot = tid + THREADS * i;   // 0..1023
                const int row = slot >> 4;            // 0..63
                const int cq  = slot & 15;            // 0..15 (float4 column)
                const float4 v = *reinterpret_cast<const float4*>(
                    emb + (size_t)(tile * 64 + row) * C + ck * 64 + cq * 4);
                *reinterpret_cast<float4*>(&elds[row * EPAD + cq * 4]) = v;
            }
            __syncthreads();

            const float* zc = zw + ck * 64;  // wave-uniform
            #pragma unroll 4
            for (int c4 = 0; c4 < 16; ++c4) {
                const float4 ev = *reinterpret_cast<const float4*>(
                    &elds[lane * EPAD + c4 * 4]);
                #pragma unroll
                for (int t = 0; t < 8; ++t) {
                    const float4 zv = *reinterpret_cast<const float4*>(
                        zc + t * C + c4 * 4);  // uniform -> s_load_dwordx4
                    acc[t] = fmaf(zv.x, ev.x, acc[t]);
                    acc[t] = fmaf(zv.y, ev.y, acc[t]);
                    acc[t] = fmaf(zv.z, ev.z, acc[t]);
                    acc[t] = fmaf(zv.w, ev.w, acc[t]);
                }
            }
        }

        const int code = tile * 64 + lane;
        const float h = hn[code];
        #pragma unroll
        for (int t = 0; t < 8; ++t) {
            const float s = h - acc[t];
            if (s < best_s[t] || (s == best_s[t] && code < best_i[t])) {
                best_s[t] = s;
                best_i[t] = code;
            }
        }
    }

    // per-token reduce across 64 lanes (lowest index wins ties), then gather
    #pragma unroll 1
    for (int t = 0; t < 8; ++t) {
        float s = best_s[t];
        int bi = best_i[t];
        #pragma unroll
        for (int off = 32; off; off >>= 1) {
            const float os = __shfl_down(s, off);
            const int oi = __shfl_down(bi, off);
            if (os < s || (os == s && oi < bi)) { s = os; bi = oi; }
        }
        bi = __shfl(bi, 0);
        const float4 v = *reinterpret_cast<const float4*>(
            emb + (size_t)bi * C + lane * 4);
        *reinterpret_cast<float4*>(
            out + (size_t)(token_base + t) * C + lane * 4) = v;
    }
}

extern "C" void kernel_launch(void* const* d_in, const int* in_sizes, int n_in,
                              void* d_out, int out_size, void* d_ws, size_t ws_size,
                              hipStream_t stream) {
    const float* z = (const float*)d_in[0];
    const float* emb = (const float*)d_in[1];
    float* out = (float*)d_out;
    float* hn = (float*)d_ws;  // K floats = 32 KB

    const int N = in_sizes[0] / C;  // 16384 tokens
    const int K = in_sizes[1] / C;  // 8192 codes

    vq_norms<<<K, 64, 0, stream>>>(emb, hn);
    vq_main<<<N / 64, THREADS, 0, stream>>>(z, emb, hn, out, K);
}

// Round 2
// 873.392 us; speedup vs baseline: 4.1339x; 4.1339x over previous
//
#include <hip/hip_runtime.h>

// VQ nearest-codebook search, fp32 register-tiled GEMM + argmin.
// score(n,k) = 0.5*|e_k|^2 - z_n.e_k  (monotone in squared distance)
//
// vq_norms : hn[k] = 0.5*|e_k|^2
// vq_main  : grid (N/64 token-tiles) x (4 K-splits). Block 256 thr (4 waves),
//            each thread an 8x8 (token x code) tile. LDS: k4-major float4
//            tiles (transpose-free staging, conflict-free b128 reads).
//            Per-split best (score,idx) per token -> ws.
// vq_final : combine 4 split-candidates per token, gather embedding row.

#define C 256
#define C4 64            // float4 per row
#define THREADS 256
#define BT 64            // tokens per block
#define NT 256           // codes per n-tile
#define KC4 8            // k-chunk = 8 float4 = 32 floats
#define NSPLIT 4
#define ESTRIDE 258      // f4 stride per k4-row of e tile (256 + 2 pad)
#define ZSTRIDE 65       // f4 stride per k4-row of z tile (64 + 1 pad)

__global__ __launch_bounds__(64) void vq_norms(const float* __restrict__ emb,
                                               float* __restrict__ hn) {
    const int k = blockIdx.x;
    const int lane = threadIdx.x;
    const float4 v = *reinterpret_cast<const float4*>(emb + (size_t)k * C + lane * 4);
    float s = v.x * v.x + v.y * v.y + v.z * v.z + v.w * v.w;
    #pragma unroll
    for (int off = 32; off; off >>= 1) s += __shfl_down(s, off);
    if (lane == 0) hn[k] = 0.5f * s;
}

__global__ __launch_bounds__(THREADS, 3) void vq_main(
    const float* __restrict__ z, const float* __restrict__ emb,
    const float* __restrict__ hn, float* __restrict__ bs,
    int* __restrict__ bia, int K, int Ntok) {
    __shared__ float4 e_t[KC4][ESTRIDE];
    __shared__ float4 z_t[KC4][ZSTRIDE];

    const int tid = threadIdx.x;
    const int tx = tid & 31;          // code lane
    const int ty = tid >> 5;          // token group (8 tokens each)
    const int sp = blockIdx.x & (NSPLIT - 1);
    const int tbase = (blockIdx.x >> 2) * BT;
    const int kps = K / NSPLIT;       // codes per split (2048)
    const int sbase = sp * kps;

    const float4* zf4 = reinterpret_cast<const float4*>(z);
    const float4* ef4 = reinterpret_cast<const float4*>(emb);

    // staging thread mappings
    const int zg = tid >> 2, zh = tid & 3;   // token, k4-pair
    const int eg = tid >> 3, eh = tid & 7;   // code lane, k4

    float best_s[8];
    int best_i[8];
    #pragma unroll
    for (int j = 0; j < 8; ++j) { best_s[j] = 3.4e38f; best_i[j] = 0; }

    #pragma unroll 1
    for (int nt = 0; nt < 2048 / NT; ++nt) {
        const int nbase = sbase + nt * NT;
        float acc[8][8] = {};

        #pragma unroll 1
        for (int ck = 0; ck < C4 / KC4; ++ck) {
            __syncthreads();
            // stage z chunk: [8 k4][64 tokens]
            #pragma unroll
            for (int i = 0; i < 2; ++i) {
                const int k4 = zh * 2 + i;
                z_t[k4][zg] = zf4[(size_t)(tbase + zg) * C4 + ck * KC4 + k4];
            }
            // stage e chunk: [8 k4][256 codes]
            #pragma unroll
            for (int p = 0; p < 8; ++p) {
                const int code = p * 32 + eg;
                e_t[eh][code] = ef4[(size_t)(nbase + code) * C4 + ck * KC4 + eh];
            }
            __syncthreads();

            #pragma unroll 2
            for (int k4 = 0; k4 < KC4; ++k4) {
                float4 zv[8], ev[8];
                #pragma unroll
                for (int j = 0; j < 8; ++j) zv[j] = z_t[k4][ty * 8 + j];
                #pragma unroll
                for (int m = 0; m < 8; ++m) ev[m] = e_t[k4][m * 32 + tx];
                #pragma unroll
                for (int j = 0; j < 8; ++j) {
                    #pragma unroll
                    for (int m = 0; m < 8; ++m) {
                        acc[j][m] = fmaf(zv[j].x, ev[m].x, acc[j][m]);
                        acc[j][m] = fmaf(zv[j].y, ev[m].y, acc[j][m]);
                        acc[j][m] = fmaf(zv[j].z, ev[m].z, acc[j][m]);
                        acc[j][m] = fmaf(zv[j].w, ev[m].w, acc[j][m]);
                    }
                }
            }
        }

        // epilogue: fold this n-tile into running argmin (codes ascending)
        #pragma unroll
        for (int m = 0; m < 8; ++m) {
            const int code = nbase + m * 32 + tx;
            const float h = hn[code];
            #pragma unroll
            for (int j = 0; j < 8; ++j) {
                const float s = h - acc[j][m];
                if (s < best_s[j]) { best_s[j] = s; best_i[j] = code; }
            }
        }
    }

    // reduce across the 32 code-lanes (xor masks <=16 stay in each half-wave)
    #pragma unroll 1
    for (int j = 0; j < 8; ++j) {
        float s = best_s[j];
        int b = best_i[j];
        #pragma unroll
        for (int off = 16; off; off >>= 1) {
            const float os = __shfl_xor(s, off);
            const int ob = __shfl_xor(b, off);
            if (os < s || (os == s && ob < b)) { s = os; b = ob; }
        }
        if (tx == 0) {
            const int token = tbase + ty * 8 + j;
            bs[sp * Ntok + token] = s;
            bia[sp * Ntok + token] = b;
        }
    }
}

__global__ __launch_bounds__(256) void vq_final(const float* __restrict__ emb,
                                                const float* __restrict__ bs,
                                                const int* __restrict__ bia,
                                                float* __restrict__ out, int Ntok) {
    const int token = blockIdx.x * 4 + (threadIdx.x >> 6);
    const int lane = threadIdx.x & 63;
    float best = 3.4e38f;
    int b = 0;
    #pragma unroll
    for (int s = 0; s < NSPLIT; ++s) {  // ascending split = ascending codes
        const float sc = bs[s * Ntok + token];
        const int ii = bia[s * Ntok + token];
        if (sc < best) { best = sc; b = ii; }
    }
    const float4* ef4 = reinterpret_cast<const float4*>(emb);
    float4* of4 = reinterpret_cast<float4*>(out);
    of4[(size_t)token * C4 + lane] = ef4[(size_t)b * C4 + lane];
}

extern "C" void kernel_launch(void* const* d_in, const int* in_sizes, int n_in,
                              void* d_out, int out_size, void* d_ws, size_t ws_size,
                              hipStream_t stream) {
    const float* z = (const float*)d_in[0];
    const float* emb = (const float*)d_in[1];
    float* out = (float*)d_out;

    const int N = in_sizes[0] / C;  // 16384 tokens
    const int K = in_sizes[1] / C;  // 8192 codes

    float* hn = (float*)d_ws;              // K floats
    float* bs = hn + K;                    // NSPLIT*N floats
    int* bia = (int*)(bs + NSPLIT * N);    // NSPLIT*N ints  (total ~544 KB)

    vq_norms<<<K, 64, 0, stream>>>(emb, hn);
    vq_main<<<(N / BT) * NSPLIT, THREADS, 0, stream>>>(z, emb, hn, bs, bia, K, N);
    vq_final<<<N / 4, 256, 0, stream>>>(emb, bs, bia, out, N);
}